// Round 2
// baseline (1495.585 us; speedup 1.0000x reference)
//
#include <hip/hip_runtime.h>
#include <stdint.h>
#include <math.h>

#define HW    524288      // 512*1024 pixels (2^19)
#define NETA  7
#define F     68          // NPROG*LEV
#define OC    17          // outputs per thread (F/4) -- fallback kernel

// ---------------- threefry2x32, key = (0, 42)  [jax.random.key(42)] ----------------
// jax_threefry_partitionable=True (default): counter=(0,i), bits = o0 ^ o1.
// Verified bit-exact vs np reference (absmax 0.0 in prior rounds).
__device__ __forceinline__ uint32_t threefry_xor_k42(uint32_t x0, uint32_t x1) {
  const uint32_t ks0 = 0u;
  const uint32_t ks1 = 42u;
  const uint32_t ks2 = 0x1BD11BDAu ^ ks0 ^ ks1;
  x0 += ks0; x1 += ks1;
#define RND(r) { x0 += x1; x1 = (x1 << (r)) | (x1 >> (32 - (r))); x1 ^= x0; }
  RND(13) RND(15) RND(26) RND(6)   x0 += ks1; x1 += ks2 + 1u;
  RND(17) RND(29) RND(16) RND(24)  x0 += ks2; x1 += ks0 + 2u;
  RND(13) RND(15) RND(26) RND(6)   x0 += ks0; x1 += ks1 + 3u;
  RND(17) RND(29) RND(16) RND(24)  x0 += ks1; x1 += ks2 + 4u;
  RND(13) RND(15) RND(26) RND(6)   x0 += ks2; x1 += ks0 + 5u;
#undef RND
  return x0 ^ x1;
}

// Shared eta-sampling logic: categorical via exponential race.
// argmax_k [gumbel_k + log(T[r,k]+1e-9)] == argmin_k [(-ln u_k)/(T[r,k]+1e-9)]
__device__ __forceinline__ int sample_eta(int p, int r,
                                          const float* rinv32,
                                          const double* rinv64) {
  float w[NETA];
#pragma unroll
  for (int k = 0; k < NETA; k++) {
    const uint32_t bits = threefry_xor_k42(0u, (uint32_t)(7 * p + k));
    const float f = __uint_as_float((bits >> 9) | 0x3f800000u) - 1.0f;
    const float u = (f == 0.0f) ? 1.1754943508222875e-38f : f;
    w[k] = (-__log2f(u)) * rinv32[r * NETA + k];
  }
  float w1 = w[0], w2 = 3.4e38f;
  int e = 0;
#pragma unroll
  for (int k = 1; k < NETA; k++) {
    if (w[k] < w1)      { w2 = w1; w1 = w[k]; e = k; }
    else if (w[k] < w2) { w2 = w[k]; }
  }
  if (!((w2 - w1) > 3e-5f * w2)) {           // ambiguous -> exact f64 race (rare)
    double b1 = 1e300;
    e = 0;
    for (int k = 0; k < NETA; k++) {
      const uint32_t bits = threefry_xor_k42(0u, (uint32_t)(7 * p + k));
      const float f = __uint_as_float((bits >> 9) | 0x3f800000u) - 1.0f;
      const double u = (f == 0.0f) ? (double)1.1754943508222875e-38f : (double)f;
      const double wv = -log(u) * rinv64[r * NETA + k];
      if (wv < b1) { b1 = wv; e = k; }
    }
  }
  return e;
}

// ---------------- kernel 1: eta sampling + per-expert global histogram ----------------
__global__ void __launch_bounds__(256) eta_count_kernel(const float* __restrict__ T,
                                                        const int* __restrict__ eta,
                                                        int* __restrict__ eta_new,
                                                        int* __restrict__ counts) {
  __shared__ float  rinv32[NETA * NETA];
  __shared__ double rinv64[NETA * NETA];
  const int tid = threadIdx.x;
  if (tid < NETA * NETA) {
    double d = 1.0 / ((double)T[tid] + 1e-9);
    rinv64[tid] = d;
    rinv32[tid] = (float)d;
  }
  __syncthreads();

  const int p = blockIdx.x * 256 + tid;
  const int e = sample_eta(p, eta[p], rinv32, rinv64);
  eta_new[p] = e;

  // wave-aggregated histogram: one atomic per expert per wave
  const int lane = tid & 63;
#pragma unroll
  for (int k = 0; k < NETA; k++) {
    const unsigned long long m = __ballot(e == k);
    if (m && lane == (__ffsll(m) - 1))
      atomicAdd(&counts[k], (int)__popcll(m));
  }
}

// ---------------- kernel 2: scatter pixel indices into expert buckets ----------------
// Each wave owns 1024 consecutive pixels (16 rounds of 64) -> per-expert runs of
// ~146 consecutive (in p) pixels per atomic chunk; keeps gathers local and out
// lines written by ~1 wave (low write amplification). perm[slot] = (e<<19)|p.
__global__ void __launch_bounds__(256) scatter_kernel(const int* __restrict__ eta_new,
                                                      const int* __restrict__ counts,
                                                      int* __restrict__ cursors,
                                                      int* __restrict__ perm) {
  const int lane = threadIdx.x & 63;
  const int wid  = (blockIdx.x * 256 + threadIdx.x) >> 6;   // 0..511

  int myE[16];
#pragma unroll
  for (int j = 0; j < 16; j++)
    myE[j] = eta_new[wid * 1024 + j * 64 + lane];

  // exclusive scan of counts (uniform across all threads)
  int base_e[NETA];
  {
    int a = 0;
#pragma unroll
    for (int k = 0; k < NETA; k++) { base_e[k] = a; a += counts[k]; }
  }

#pragma unroll 1
  for (int e = 0; e < NETA; e++) {
    int pre[16];
    int total = 0;
#pragma unroll
    for (int j = 0; j < 16; j++) {
      pre[j] = total;
      total += (int)__popcll(__ballot(myE[j] == e));
    }
    int wbase = 0;
    if (lane == 0) wbase = atomicAdd(&cursors[e], total);
    wbase = __shfl(wbase, 0) + base_e[e];
#pragma unroll
    for (int j = 0; j < 16; j++) {
      const unsigned long long m = __ballot(myE[j] == e);
      if (myE[j] == e) {
        const int rank = (int)__popcll(m & ((1ull << lane) - 1));
        perm[wbase + pre[j] + rank] = (e << 19) | (wid * 1024 + j * 64 + lane);
      }
    }
  }
}

// ---------------- kernel 3: bucketed matvec, wave-uniform expert ----------------
// lane = one pixel, all 68 outputs. e is wave-uniform (except <=6 bucket-boundary
// waves, handled by the <=7-pass masked loop). W/bias come through the scalar
// cache (s_load): the inner loop is v_fmac v,s,v -- no LDS, no per-lane W traffic.
// Accumulation order = f ascending fmaf chain, bias added last (bit-identical to
// the round-1 kernel that scored absmax 0.0).
__global__ void __launch_bounds__(256, 4) expert_bucket_kernel(const float* __restrict__ x,
                                                               const float* __restrict__ W,
                                                               const float* __restrict__ b,
                                                               const int* __restrict__ perm,
                                                               float* __restrict__ out) {
  const int s  = blockIdx.x * 256 + threadIdx.x;
  const int pk = perm[s];
  const int p  = pk & (HW - 1);
  const int e  = pk >> 19;

  bool rem = true;
  while (__any(rem)) {
    const unsigned long long mm = __ballot(rem);
    const int lead = __ffsll(mm) - 1;
    const int e0   = __builtin_amdgcn_readfirstlane(__shfl(e, lead));
    const bool go  = rem && (e == e0);
    if (go) {
      float xv[F];
#pragma unroll
      for (int f = 0; f < F; f++) xv[f] = x[(size_t)f * HW + p];

      const float* __restrict__ wb = W + (size_t)e0 * (F * F);
      const float* __restrict__ bb = b + e0 * F;

#pragma unroll 1
      for (int og = 0; og < F; og += 4) {
        float a0 = 0.0f, a1 = 0.0f, a2 = 0.0f, a3 = 0.0f;
#pragma unroll
        for (int f = 0; f < F; f++) {
          const float xf = xv[f];
          a0 = fmaf(wb[(size_t)(og + 0) * F + f], xf, a0);
          a1 = fmaf(wb[(size_t)(og + 1) * F + f], xf, a1);
          a2 = fmaf(wb[(size_t)(og + 2) * F + f], xf, a2);
          a3 = fmaf(wb[(size_t)(og + 3) * F + f], xf, a3);
        }
        out[(size_t)(og + 0) * HW + p] = a0 + bb[og + 0];
        out[(size_t)(og + 1) * HW + p] = a1 + bb[og + 1];
        out[(size_t)(og + 2) * HW + p] = a2 + bb[og + 2];
        out[(size_t)(og + 3) * HW + p] = a3 + bb[og + 3];
      }
    }
    rem = rem && !go;
  }
}

// ================= fallback path (ws too small): round-1 kernels =================
#define WSTRIDE 4628
#define WLDS_W  (6 * WSTRIDE + 4624)
#define LDS_TOT (WLDS_W + NETA * F)

__global__ void __launch_bounds__(256) eta_kernel_fb(const float* __restrict__ T,
                                                     const int* __restrict__ eta,
                                                     int* __restrict__ eta_new) {
  __shared__ float  rinv32[NETA * NETA];
  __shared__ double rinv64[NETA * NETA];
  const int tid = threadIdx.x;
  if (tid < NETA * NETA) {
    double d = 1.0 / ((double)T[tid] + 1e-9);
    rinv64[tid] = d;
    rinv32[tid] = (float)d;
  }
  __syncthreads();
  const int p = blockIdx.x * 256 + tid;
  eta_new[p] = sample_eta(p, eta[p], rinv32, rinv64);
}

__global__ void __launch_bounds__(256, 1) expert_kernel_fb(const float* __restrict__ x,
                                                           const float* __restrict__ W,
                                                           const float* __restrict__ b,
                                                           const int* __restrict__ eta_new,
                                                           float* __restrict__ out) {
  __shared__ __align__(16) float wlds[LDS_TOT];
  const int tid = threadIdx.x;
#pragma unroll
  for (int e = 0; e < NETA; e++) {
    const float* __restrict__ src = W + (size_t)e * (F * F);
    float* dst = wlds + e * WSTRIDE;
    for (int i = tid; i < (F * F) / 4; i += 256)
      *reinterpret_cast<float4*>(dst + 4 * i) =
          *reinterpret_cast<const float4*>(src + 4 * i);
  }
  for (int i = tid; i < NETA * F; i += 256) wlds[WLDS_W + i] = b[i];
  __syncthreads();

  const int pl = tid & 63;
  const int c  = tid >> 6;
  for (int tile = blockIdx.x; tile < HW / 64; tile += gridDim.x) {
    const int p = tile * 64 + pl;
    const int e = eta_new[p];
    float xv[F];
#pragma unroll
    for (int f = 0; f < F; f++) xv[f] = x[(size_t)f * HW + p];
    const float* wp = wlds + e * WSTRIDE + (c * OC) * F;
    float acc[OC];
#pragma unroll
    for (int o = 0; o < OC; o++) acc[o] = 0.0f;
#pragma unroll
    for (int f4 = 0; f4 < F / 4; f4++) {
      const float x0 = xv[4 * f4 + 0];
      const float x1 = xv[4 * f4 + 1];
      const float x2 = xv[4 * f4 + 2];
      const float x3 = xv[4 * f4 + 3];
#pragma unroll
      for (int o = 0; o < OC; o++) {
        const float4 w = *reinterpret_cast<const float4*>(wp + o * F + 4 * f4);
        float a = acc[o];
        a = fmaf(w.x, x0, a);
        a = fmaf(w.y, x1, a);
        a = fmaf(w.z, x2, a);
        a = fmaf(w.w, x3, a);
        acc[o] = a;
      }
    }
#pragma unroll
    for (int o = 0; o < OC; o++)
      out[(size_t)(c * OC + o) * HW + p] = acc[o] + wlds[WLDS_W + e * F + c * OC + o];
  }
}

extern "C" void kernel_launch(void* const* d_in, const int* in_sizes, int n_in,
                              void* d_out, int out_size, void* d_ws, size_t ws_size,
                              hipStream_t stream) {
  const float* x   = (const float*)d_in[0];
  const float* W   = (const float*)d_in[1];
  const float* b   = (const float*)d_in[2];
  const float* T   = (const float*)d_in[3];
  const int*   eta = (const int*)d_in[4];
  float* out = (float*)d_out;

  const size_t need = 16 * sizeof(int) + 2 * (size_t)HW * sizeof(int);
  if (ws_size >= need) {
    int* counts  = (int*)d_ws;          // [0..6] histogram, [7] pad
    int* cursors = counts + 8;          // [8..14] cursors, [15] pad
    int* eta_new = counts + 16;
    int* perm    = eta_new + HW;
    hipMemsetAsync(counts, 0, 16 * sizeof(int), stream);
    eta_count_kernel<<<HW / 256, 256, 0, stream>>>(T, eta, eta_new, counts);
    scatter_kernel<<<HW / 1024 / 4, 256, 0, stream>>>(eta_new, counts, cursors, perm);
    expert_bucket_kernel<<<HW / 256, 256, 0, stream>>>(x, W, b, perm, out);
  } else {
    int* etabuf = (ws_size >= sizeof(int) * (size_t)HW)
                      ? (int*)d_ws
                      : ((int*)d_out) + (size_t)(F - 1) * HW;
    eta_kernel_fb<<<HW / 256, 256, 0, stream>>>(T, eta, etabuf);
    expert_kernel_fb<<<1024, 256, 0, stream>>>(x, W, b, etabuf, out);
  }
}

// Round 3
// 726.525 us; speedup vs baseline: 2.0585x; 2.0585x over previous
//
#include <hip/hip_runtime.h>
#include <stdint.h>
#include <math.h>

#define HW    524288      // 512*1024 pixels (2^19)
#define NETA  7
#define F     68          // NPROG*LEV
#define TILE  512         // pixels per block == threads per block
#define NW    8           // waves per block

// ---------------- threefry2x32, key = (0, 42)  [jax.random.key(42)] ----------------
// jax_threefry_partitionable=True (default): counter=(0,i), bits = o0 ^ o1.
// Verified bit-exact vs np reference (absmax 0.0 rounds 0-2).
__device__ __forceinline__ uint32_t threefry_xor_k42(uint32_t x0, uint32_t x1) {
  const uint32_t ks0 = 0u;
  const uint32_t ks1 = 42u;
  const uint32_t ks2 = 0x1BD11BDAu ^ ks0 ^ ks1;
  x0 += ks0; x1 += ks1;
#define RND(r) { x0 += x1; x1 = (x1 << (r)) | (x1 >> (32 - (r))); x1 ^= x0; }
  RND(13) RND(15) RND(26) RND(6)   x0 += ks1; x1 += ks2 + 1u;
  RND(17) RND(29) RND(16) RND(24)  x0 += ks2; x1 += ks0 + 2u;
  RND(13) RND(15) RND(26) RND(6)   x0 += ks0; x1 += ks1 + 3u;
  RND(17) RND(29) RND(16) RND(24)  x0 += ks1; x1 += ks2 + 4u;
  RND(13) RND(15) RND(26) RND(6)   x0 += ks2; x1 += ks0 + 5u;
#undef RND
  return x0 ^ x1;
}

// categorical via exponential race: argmin_k [(-ln u_k)/(T[r,k]+1e-9)]
// f32 screen with hw log2; exact f64 fallback when top-2 gap ambiguous (rare).
__device__ __forceinline__ int sample_eta(int p, int r,
                                          const float* rinv32,
                                          const double* rinv64) {
  float w[NETA];
#pragma unroll
  for (int k = 0; k < NETA; k++) {
    const uint32_t bits = threefry_xor_k42(0u, (uint32_t)(7 * p + k));
    const float f = __uint_as_float((bits >> 9) | 0x3f800000u) - 1.0f;
    const float u = (f == 0.0f) ? 1.1754943508222875e-38f : f;
    w[k] = (-__log2f(u)) * rinv32[r * NETA + k];
  }
  float w1 = w[0], w2 = 3.4e38f;
  int e = 0;
#pragma unroll
  for (int k = 1; k < NETA; k++) {
    if (w[k] < w1)      { w2 = w1; w1 = w[k]; e = k; }
    else if (w[k] < w2) { w2 = w[k]; }
  }
  if (!((w2 - w1) > 3e-5f * w2)) {
    double b1 = 1e300;
    e = 0;
    for (int k = 0; k < NETA; k++) {
      const uint32_t bits = threefry_xor_k42(0u, (uint32_t)(7 * p + k));
      const float f = __uint_as_float((bits >> 9) | 0x3f800000u) - 1.0f;
      const double u = (f == 0.0f) ? (double)1.1754943508222875e-38f : (double)f;
      const double wv = -log(u) * rinv64[r * NETA + k];
      if (wv < b1) { b1 = wv; e = k; }
    }
  }
  return e;
}

// ---------------- fused kernel: sample -> block-local sort -> scalar-W matvec ----------------
// Block = 512 threads = 512 consecutive pixels. Sort pixels by expert WITHIN the
// block (ballot ranks, no atomics): waves see ~1.75 distinct experts instead of 7,
// so W streams through the scalar pipe (s_load, wave-uniform e0) with ~1.75x
// masked-pass overhead. x gathers stay inside the block's 2KB/row window (every
// HBM line fully consumed); out staged in LDS per 17-row chunk, flushed coalesced
// (no partial-line RMW). No global atomics, no workspace, single launch.
__global__ void __launch_bounds__(512, 4) fused_kernel(const float* __restrict__ x,
                                                       const float* __restrict__ W,
                                                       const float* __restrict__ b,
                                                       const float* __restrict__ T,
                                                       const int* __restrict__ eta,
                                                       float* __restrict__ out) {
  __shared__ float  rinv32[NETA * NETA];
  __shared__ double rinv64[NETA * NETA];
  __shared__ int    cnt[NETA * NW];     // [expert][wave] chunk counts
  __shared__ int    tot[NETA];          // per-expert totals
  __shared__ int    sidx[TILE];         // sorted slot -> (e<<9)|local_pixel
  __shared__ float  olds[17 * TILE];    // out staging for one 17-row o-chunk (34.8 KB)

  const int tid  = threadIdx.x;
  const int lane = tid & 63;
  const int w    = tid >> 6;
  const int blkbase = blockIdx.x * TILE;

  if (tid < NETA * NETA) {
    double d = 1.0 / ((double)T[tid] + 1e-9);
    rinv64[tid] = d;
    rinv32[tid] = (float)d;
  }
  __syncthreads();

  // ---- sample (1 pixel per thread; eta_new lives only in registers) ----
  const int p = blkbase + tid;
  const int e = sample_eta(p, eta[p], rinv32, rinv64);

  // ---- ballot-rank counting sort over 7 experts ----
  int myrank = 0;
#pragma unroll
  for (int k = 0; k < NETA; k++) {
    const unsigned long long mk = __ballot(e == k);
    if (e == k) myrank = (int)__popcll(mk & ((1ull << lane) - 1ull));
    if (lane == 0) cnt[k * NW + w] = (int)__popcll(mk);
  }
  __syncthreads();
  if (tid < NETA) {
    int s = 0;
#pragma unroll
    for (int j = 0; j < NW; j++) s += cnt[tid * NW + j];
    tot[tid] = s;
  }
  __syncthreads();
  int off = myrank;
#pragma unroll
  for (int k = 0; k < NETA; k++) if (k < e) off += tot[k];
#pragma unroll
  for (int j = 0; j < NW; j++) if (j < w) off += cnt[e * NW + j];
  sidx[off] = (e << 9) | tid;
  __syncthreads();

  // ---- my sorted slot: expert nearly wave-uniform now ----
  const int v  = sidx[w * 64 + lane];
  const int se = v >> 9;
  const int lp = v & (TILE - 1);

  // full x column for my pixel (reused across all 4 o-chunks & passes)
  float xv[F];
#pragma unroll
  for (int f = 0; f < F; f++) xv[f] = x[(size_t)f * HW + blkbase + lp];

  for (int oc = 0; oc < 4; oc++) {
    const int o0 = oc * 17;

    bool active = true;
    while (__any(active)) {
      const unsigned long long mm = __ballot(active);
      const int lead = (int)__ffsll(mm) - 1;
      const int e0   = __builtin_amdgcn_readfirstlane(__shfl(se, lead));
      const bool go  = active && (se == e0);
      if (go) {
        // wave-uniform W/bias base -> scalar loads
        const float* __restrict__ wb = W + (size_t)e0 * (F * F) + (size_t)o0 * F;
        const float* __restrict__ bb = b + (size_t)e0 * F + o0;

        // 17 outputs as 4 groups of 4 + 1 (4 indep fmaf chains per group).
        // Chain order per output: f ascending, bias last (bit-identical to r1).
#pragma unroll
        for (int ig = 0; ig < 4; ig++) {
          const int i0 = ig * 4;
          float a0 = 0.0f, a1 = 0.0f, a2 = 0.0f, a3 = 0.0f;
#pragma unroll
          for (int f = 0; f < F; f++) {
            const float xf = xv[f];
            a0 = fmaf(wb[(size_t)(i0 + 0) * F + f], xf, a0);
            a1 = fmaf(wb[(size_t)(i0 + 1) * F + f], xf, a1);
            a2 = fmaf(wb[(size_t)(i0 + 2) * F + f], xf, a2);
            a3 = fmaf(wb[(size_t)(i0 + 3) * F + f], xf, a3);
          }
          olds[(i0 + 0) * TILE + lp] = a0 + bb[i0 + 0];
          olds[(i0 + 1) * TILE + lp] = a1 + bb[i0 + 1];
          olds[(i0 + 2) * TILE + lp] = a2 + bb[i0 + 2];
          olds[(i0 + 3) * TILE + lp] = a3 + bb[i0 + 3];
        }
        {
          float a = 0.0f;
#pragma unroll
          for (int f = 0; f < F; f++) a = fmaf(wb[(size_t)16 * F + f], xv[f], a);
          olds[16 * TILE + lp] = a + bb[16];
        }
      }
      active = active && !go;
    }

    __syncthreads();
    // coalesced flush of 17 completed rows
#pragma unroll
    for (int i = 0; i < 17; i++)
      out[(size_t)(o0 + i) * HW + blkbase + tid] = olds[i * TILE + tid];
    __syncthreads();
  }
}

extern "C" void kernel_launch(void* const* d_in, const int* in_sizes, int n_in,
                              void* d_out, int out_size, void* d_ws, size_t ws_size,
                              hipStream_t stream) {
  const float* x   = (const float*)d_in[0];
  const float* W   = (const float*)d_in[1];
  const float* b   = (const float*)d_in[2];
  const float* T   = (const float*)d_in[3];
  const int*   eta = (const int*)d_in[4];
  float* out = (float*)d_out;

  fused_kernel<<<HW / TILE, TILE, 0, stream>>>(x, W, b, T, eta, out);
}